// Round 5
// baseline (86.681 us; speedup 1.0000x reference)
//
#include <hip/hip_runtime.h>

// LinearAttention fused pipeline, MI355X gfx950. Round 5.
// k_init:  w_qkv->wh f16, w_out->wouth f16, zero kv/den
// k_kvt:   read x f32 direct; LDS-transpose 64n x 256c tile once; write xh
//          f16 side-product; K,V GEMMs vs LDS-staged W; kv/den in-register
//          reduction -> atomics. (transpose kernel eliminated)
// k_fused2: 512thr/8 waves. qT = Wq.xhT -> elu1*s*1024 -> Q-LDS ->
//          out = wouth.Q -> fused LayerNorm -> d_out.

#define NB 16
#define NC 256
#define NN 4096
#define LN_EPS 1e-5f
#define IOSCALE (1.0f/1024.0f)

typedef _Float16 f16;
typedef _Float16 f16x8 __attribute__((ext_vector_type(8)));
typedef _Float16 f16x4v __attribute__((ext_vector_type(4)));
typedef float f32x4 __attribute__((ext_vector_type(4)));

typedef __attribute__((address_space(1))) const unsigned int* as1cu32;
typedef __attribute__((address_space(3))) unsigned int* as3u32;

__device__ __forceinline__ void gload16(const void* g, void* l) {
  __builtin_amdgcn_global_load_lds((as1cu32)g, (as3u32)l, 16, 0, 0);
}

__device__ __forceinline__ float elu1(float x) {
  return x > 0.f ? x + 1.f : __expf(x);
}

// Swizzled fragment address (halves) in a [rows][64]-f16 LDS tile.
__device__ __forceinline__ int swz(int row, int unit) {
  return row * 64 + (((unit) ^ (row & 7)) << 3);
}

__global__ __launch_bounds__(256) void k_init(const float* __restrict__ wqkv,
                                              const float* __restrict__ wout,
                                              f16* __restrict__ wh,
                                              f16* __restrict__ wouth,
                                              float* __restrict__ kvden) {
  int i = blockIdx.x * 256 + threadIdx.x;   // grid covers 768*256 exactly
  wh[i] = (f16)wqkv[i];
  if (i < 65536) wouth[i] = (f16)wout[i];
  if (i < 8192) kvden[i] = 0.f;
}

// Block: 64 pixels x all 256 channels. 512 thr = 8 waves = 2 ng x 4 cg.
// Xt[64n][264c] staged once from x (f32->f16 transpose); xh written out;
// then K,V GEMM sweeps with Bt re-staged per 64-K chunk.
__global__ __launch_bounds__(512) void k_kvt(const float* __restrict__ x,
                                             const f16* __restrict__ wh,
                                             f16* __restrict__ xh,
                                             float* __restrict__ kv,
                                             float* __restrict__ den) {
  __shared__ __align__(16) f16 Xt[64 * 264];   // 33.8 KB, padded rows
  __shared__ __align__(16) f16 Bt[256 * 64];   // 32 KB (Wk then Wv chunks)
  const int b = blockIdx.y;
  const int n0 = blockIdx.x * 64;
  const int tid = threadIdx.x;
  const int lane = tid & 63;
  const int wv = tid >> 6;          // 0..7
  const int ng = wv >> 2;           // n-subtile (32n)
  const int cg = wv & 3;            // channel group (64ch)
  const int l15 = lane & 15, lg = lane >> 4;
  const int lr = lane >> 3;
  const int ssrc = ((lane & 7) ^ lr) * 8;

  // ---- stage x[b][c][n0:n0+64] f32 -> Xt[n][c] f16 (transpose) ----
  {
    const int c = tid >> 1;
    const int nh = (tid & 1) * 32;
    const float* xp = x + ((size_t)(b * NC + c)) * NN + n0 + nh;
#pragma unroll
    for (int i = 0; i < 8; ++i) {
      const float4 v4 = *reinterpret_cast<const float4*>(xp + i * 4);
      const int nb = nh + i * 4;
      Xt[(nb + 0) * 264 + c] = (f16)v4.x;
      Xt[(nb + 1) * 264 + c] = (f16)v4.y;
      Xt[(nb + 2) * 264 + c] = (f16)v4.z;
      Xt[(nb + 3) * 264 + c] = (f16)v4.w;
    }
  }
  __syncthreads();

  // ---- write xh[b][n][c] side-product (coalesced b128) ----
  {
    const int r = tid >> 3;
    const int s = (tid & 7) * 32;
#pragma unroll
    for (int q = 0; q < 4; ++q) {
      const f16x8 h = *(const f16x8*)(Xt + r * 264 + s + q * 8);
      *reinterpret_cast<f16x8*>(&xh[((size_t)(b * NN + n0 + r)) * NC + s + q * 8]) = h;
    }
  }

  f32x4 kacc[2][4] = {};
  f32x4 vacc[2][4] = {};

  for (int ks = 0; ks < 4; ++ks) {
    const int c0 = ks * 64;
    __syncthreads();
#pragma unroll
    for (int it = 0; it < 4; ++it) {
      const int seg = wv * 4 + it;
      gload16(wh + (size_t)(256 + seg * 8 + lr) * NC + c0 + ssrc, Bt + seg * 512);
    }
    __syncthreads();
#pragma unroll
    for (int kk = 0; kk < 2; ++kk) {
      const int ku = kk * 4 + lg;
      const int col = c0 + kk * 32 + lg * 8;
      f16x8 af[2], bf[4];
#pragma unroll
      for (int m = 0; m < 2; ++m)
        af[m] = *(const f16x8*)(Xt + (ng * 32 + m * 16 + l15) * 264 + col);
#pragma unroll
      for (int f = 0; f < 4; ++f)
        bf[f] = *(const f16x8*)(Bt + swz(cg * 64 + f * 16 + l15, ku));
#pragma unroll
      for (int m = 0; m < 2; ++m)
#pragma unroll
        for (int f = 0; f < 4; ++f)
          kacc[m][f] = __builtin_amdgcn_mfma_f32_16x16x32_f16(af[m], bf[f], kacc[m][f], 0, 0, 0);
    }
    __syncthreads();
#pragma unroll
    for (int it = 0; it < 4; ++it) {
      const int seg = wv * 4 + it;
      gload16(wh + (size_t)(512 + seg * 8 + lr) * NC + c0 + ssrc, Bt + seg * 512);
    }
    __syncthreads();
#pragma unroll
    for (int kk = 0; kk < 2; ++kk) {
      const int ku = kk * 4 + lg;
      const int col = c0 + kk * 32 + lg * 8;
      f16x8 af[2], bf[4];
#pragma unroll
      for (int m = 0; m < 2; ++m)
        af[m] = *(const f16x8*)(Xt + (ng * 32 + m * 16 + l15) * 264 + col);
#pragma unroll
      for (int f = 0; f < 4; ++f)
        bf[f] = *(const f16x8*)(Bt + swz(cg * 64 + f * 16 + l15, ku));
#pragma unroll
      for (int m = 0; m < 2; ++m)
#pragma unroll
        for (int f = 0; f < 4; ++f)
          vacc[m][f] = __builtin_amdgcn_mfma_f32_16x16x32_f16(af[m], bf[f], vacc[m][f], 0, 0, 0);
    }
  }
  float pkv[4] = {0.f, 0.f, 0.f, 0.f}, pden[4] = {0.f, 0.f, 0.f, 0.f};
#pragma unroll
  for (int f = 0; f < 4; ++f)
#pragma unroll
    for (int m = 0; m < 2; ++m)
#pragma unroll
      for (int j = 0; j < 4; ++j) {
        const float kk = elu1(kacc[m][f][j]);
        pkv[f] += kk * vacc[m][f][j];
        pden[f] += kk;
      }
#pragma unroll
  for (int f = 0; f < 4; ++f) {
    pkv[f] += __shfl_xor(pkv[f], 16, 64);
    pkv[f] += __shfl_xor(pkv[f], 32, 64);
    pden[f] += __shfl_xor(pden[f], 16, 64);
    pden[f] += __shfl_xor(pden[f], 32, 64);
  }
  if (lane < 16) {
#pragma unroll
    for (int f = 0; f < 4; ++f) {
      const int c = cg * 64 + f * 16 + lane;
      atomicAdd(&kv[b * NC + c], pkv[f]);
      atomicAdd(&den[b * NC + c], pden[f]);
    }
  }
}

// Fused GEMM1(q)+scale+GEMM2(out)+LN. 512 thr = 8 waves = 4 cg x 2 ng.
__global__ __launch_bounds__(512) void k_fused2(const f16* __restrict__ xh,
                                                const f16* __restrict__ wh,
                                                const f16* __restrict__ wouth,
                                                const float* __restrict__ kv,
                                                const float* __restrict__ den,
                                                const float* __restrict__ gamma,
                                                const float* __restrict__ beta,
                                                float* __restrict__ out) {
  __shared__ __align__(16) f16 Wt[256 * 64];   // 32 KB (Wq chunk, then wouth chunk)
  __shared__ __align__(16) f16 Xc[64 * 64];    // 8 KB (xh chunk, swizzled)
  __shared__ __align__(16) f16 Q[64 * 264];    // 33.8 KB padded
  __shared__ float s1024[256];
  __shared__ float red1[4][64], red2[4][64];
  __shared__ float smu[64], srs[64];
  const int b = blockIdx.y;
  const int n0 = blockIdx.x * 64;
  const int tid = threadIdx.x;
  const int lane = tid & 63;
  const int wv = tid >> 6;          // 0..7
  const int cg = wv >> 1;           // o/c group (64)
  const int ng = wv & 1;            // n group (32)
  const int l15 = lane & 15, lg = lane >> 4;
  const int lr = lane >> 3;
  const int ssrc = ((lane & 7) ^ lr) * 8;

  if (tid < 256)
    s1024[tid] = kv[b * NC + tid] / fmaxf(den[b * NC + tid], 1e-6f) * 1024.0f;

  f32x4 acc[4][2] = {};   // [m = c-frag][f = n-frag]

  for (int ks = 0; ks < 4; ++ks) {
    const int c0 = ks * 64;
    __syncthreads();
    gload16(xh + ((size_t)(b * NN + n0 + wv * 8 + lr)) * NC + c0 + ssrc, Xc + wv * 512);
#pragma unroll
    for (int it = 0; it < 4; ++it) {
      const int seg = wv * 4 + it;
      gload16(wh + (size_t)(seg * 8 + lr) * NC + c0 + ssrc, Wt + seg * 512);
    }
    __syncthreads();
#pragma unroll
    for (int kk = 0; kk < 2; ++kk) {
      const int ku = kk * 4 + lg;
      f16x8 af[4], bf[2];
#pragma unroll
      for (int m = 0; m < 4; ++m)
        af[m] = *(const f16x8*)(Wt + swz(cg * 64 + m * 16 + l15, ku));
#pragma unroll
      for (int f = 0; f < 2; ++f)
        bf[f] = *(const f16x8*)(Xc + swz(ng * 32 + f * 16 + l15, ku));
#pragma unroll
      for (int m = 0; m < 4; ++m)
#pragma unroll
        for (int f = 0; f < 2; ++f)
          acc[m][f] = __builtin_amdgcn_mfma_f32_16x16x32_f16(af[m], bf[f], acc[m][f], 0, 0, 0);
    }
  }

  // q epilogue: Q[n][c] = elu1(qT) * s1024[c]
#pragma unroll
  for (int m = 0; m < 4; ++m) {
    const int cq = cg * 64 + m * 16 + lg * 4;
#pragma unroll
    for (int f = 0; f < 2; ++f) {
      const int n = ng * 32 + f * 16 + l15;
      f16x4v h;
#pragma unroll
      for (int j = 0; j < 4; ++j)
        h[j] = (f16)(elu1(acc[m][f][j]) * s1024[cq + j]);
      *reinterpret_cast<f16x4v*>(Q + n * 264 + cq) = h;
    }
  }

  f32x4 acc2[4][2] = {};  // [m = o-frag][f = n-frag]
  for (int ks = 0; ks < 4; ++ks) {
    const int c0 = ks * 64;
    __syncthreads();   // 1st iter also publishes Q
#pragma unroll
    for (int it = 0; it < 4; ++it) {
      const int seg = wv * 4 + it;
      gload16(wouth + (size_t)(seg * 8 + lr) * NC + c0 + ssrc, Wt + seg * 512);
    }
    __syncthreads();
#pragma unroll
    for (int kk = 0; kk < 2; ++kk) {
      const int ku = kk * 4 + lg;
      const int kb = c0 + kk * 32 + lg * 8;
      f16x8 af[4], bf[2];
#pragma unroll
      for (int m = 0; m < 4; ++m)
        af[m] = *(const f16x8*)(Wt + swz(cg * 64 + m * 16 + l15, ku));
#pragma unroll
      for (int f = 0; f < 2; ++f)
        bf[f] = *(const f16x8*)(Q + (ng * 32 + f * 16 + l15) * 264 + kb);
#pragma unroll
      for (int m = 0; m < 4; ++m)
#pragma unroll
        for (int f = 0; f < 2; ++f)
          acc2[m][f] = __builtin_amdgcn_mfma_f32_16x16x32_f16(af[m], bf[f], acc2[m][f], 0, 0, 0);
    }
  }

  // LayerNorm over o (256) per column n
  float s1[2] = {0, 0}, s2[2] = {0, 0};
#pragma unroll
  for (int f = 0; f < 2; ++f)
#pragma unroll
    for (int m = 0; m < 4; ++m)
#pragma unroll
      for (int j = 0; j < 4; ++j) {
        const float v = acc2[m][f][j];
        s1[f] += v;
        s2[f] += v * v;
      }
#pragma unroll
  for (int f = 0; f < 2; ++f) {
    s1[f] += __shfl_xor(s1[f], 16, 64);
    s1[f] += __shfl_xor(s1[f], 32, 64);
    s2[f] += __shfl_xor(s2[f], 16, 64);
    s2[f] += __shfl_xor(s2[f], 32, 64);
  }
  if (lane < 16) {
#pragma unroll
    for (int f = 0; f < 2; ++f) {
      red1[cg][ng * 32 + f * 16 + lane] = s1[f];
      red2[cg][ng * 32 + f * 16 + lane] = s2[f];
    }
  }
  __syncthreads();
  if (tid < 64) {
    const float a1 = red1[0][tid] + red1[1][tid] + red1[2][tid] + red1[3][tid];
    const float a2 = red2[0][tid] + red2[1][tid] + red2[2][tid] + red2[3][tid];
    const float mu = a1 * (IOSCALE / 256.f);
    const float e2 = a2 * (IOSCALE * IOSCALE / 256.f);
    smu[tid] = mu;
    srs[tid] = rsqrtf(e2 - mu * mu + LN_EPS);
  }
  __syncthreads();
#pragma unroll
  for (int m = 0; m < 4; ++m) {
    const int ob = cg * 64 + m * 16 + lg * 4;
#pragma unroll
    for (int j = 0; j < 4; ++j) {
      const int o = ob + j;
      const float g = gamma[o], be = beta[o];
#pragma unroll
      for (int f = 0; f < 2; ++f) {
        const int col = ng * 32 + f * 16 + l15;
        const float v = acc2[m][f][j] * IOSCALE;
        out[((size_t)(b * NC + o)) * NN + n0 + col] = (v - smu[col]) * srs[col] * g + be;
      }
    }
  }
}

extern "C" void kernel_launch(void* const* d_in, const int* in_sizes, int n_in,
                              void* d_out, int out_size, void* d_ws, size_t ws_size,
                              hipStream_t stream) {
  const float* x = (const float*)d_in[0];
  const float* w_qkv = (const float*)d_in[1];
  const float* w_out = (const float*)d_in[2];
  const float* ln_g = (const float*)d_in[3];
  const float* ln_b = (const float*)d_in[4];
  float* out = (float*)d_out;

  char* wsb = (char*)d_ws;
  const size_t OFF_WH = 0;                        // 768*256*2 = 393216
  const size_t OFF_WOUTH = 393216;                // 256*256*2 = 131072
  const size_t OFF_XH = OFF_WOUTH + 131072;       // 32 MiB
  const size_t OFF_KV = OFF_XH + 33554432;        // 16 KiB
  const size_t OFF_DEN = OFF_KV + 16384;          // 16 KiB

  f16* wh = (f16*)(wsb + OFF_WH);
  f16* wouth = (f16*)(wsb + OFF_WOUTH);
  f16* xh = (f16*)(wsb + OFF_XH);
  float* kv = (float*)(wsb + OFF_KV);
  float* den = (float*)(wsb + OFF_DEN);

  k_init<<<768, 256, 0, stream>>>(w_qkv, w_out, wh, wouth, kv);
  k_kvt<<<dim3(64, 16), 512, 0, stream>>>(x, wh, xh, kv, den);
  k_fused2<<<dim3(64, 16), 512, 0, stream>>>(xh, wh, wouth, kv, den, ln_g, ln_b, out);
}